// Round 12
// baseline (6295.383 us; speedup 1.0000x reference)
//
#include <hip/hip_runtime.h>

#define VOCAB 32000
#define EMBD  512
#define HIDD  1024
#define SLEN  512
#define NBAT  4
#define GATE4 4096   // 4*HIDD
#define ABLK  128    // layer-0 blocks, 8 units each
#define BBLK  128    // layer-1 blocks, 8 units each (Wk1 in LDS, Wr1 in regs)

typedef unsigned long long u64;

#define AL(p) __hip_atomic_load((p), __ATOMIC_RELAXED, __HIP_MEMORY_SCOPE_AGENT)
#define AS(p, v) __hip_atomic_store((p), (v), __ATOMIC_RELAXED, __HIP_MEMORY_SCOPE_AGENT)

// ---------------- embedding gather ----------------
__global__ void embed_k(const int* __restrict__ ids, const float* __restrict__ emb,
                        float* __restrict__ X0) {
  const int n  = blockIdx.x;             // 0..2047 (= b*SLEN + s)
  const int id = ids[n];
  ((float4*)X0)[(size_t)n*(EMBD/4) + threadIdx.x] =
      ((const float4*)emb)[(size_t)id*(EMBD/4) + threadIdx.x];
}

// ---------------- 32x32 tiled transpose: [1024][4096] -> [4096][1024] -------
__global__ __launch_bounds__(256) void transpose_k(const float* __restrict__ src,
                                                   float* __restrict__ dst) {
  __shared__ float t[32][33];
  const int bx = blockIdx.x * 32;
  const int by = blockIdx.y * 32;
  const int r0 = threadIdx.x >> 5;
  const int c  = threadIdx.x & 31;
  #pragma unroll
  for (int i = 0; i < 4; i++) {
    const int r = r0 + i*8;
    t[r][c] = src[(size_t)(by + r)*GATE4 + bx + c];
  }
  __syncthreads();
  #pragma unroll
  for (int i = 0; i < 4; i++) {
    const int rw = r0 + i*8;
    dst[(size_t)(bx + rw)*HIDD + by + c] = t[c][rw];
  }
}

// ---------------- f32 tiled GEMM: C = A@B + bias ----------------
__global__ __launch_bounds__(256) void gemm_nn_bias(
    const float* __restrict__ A, const float* __restrict__ B,
    const float* __restrict__ bias, float* __restrict__ C,
    int M, int N, int K) {
  __shared__ float As[16][64];
  __shared__ float Bs[16][64];
  const int tid = threadIdx.x;
  const int bm = blockIdx.y * 64;
  const int bn = blockIdx.x * 64;
  const int tx = tid & 15, ty = tid >> 4;
  const int mA = tid >> 2, kqA = (tid & 3) * 4;
  const int kB = tid >> 4, nB = (tid & 15) * 4;
  float acc[4][4] = {{0.f}};
  for (int k0 = 0; k0 < K; k0 += 16) {
    float4 a4 = *(const float4*)(A + (size_t)(bm + mA)*K + k0 + kqA);
    As[kqA+0][mA] = a4.x; As[kqA+1][mA] = a4.y;
    As[kqA+2][mA] = a4.z; As[kqA+3][mA] = a4.w;
    *(float4*)&Bs[kB][nB] = *(const float4*)(B + (size_t)(k0 + kB)*N + bn + nB);
    __syncthreads();
    #pragma unroll
    for (int k = 0; k < 16; k++) {
      float4 av = *(float4*)&As[k][ty*4];
      float4 bv = *(float4*)&Bs[k][tx*4];
      float ar[4] = {av.x, av.y, av.z, av.w};
      float br[4] = {bv.x, bv.y, bv.z, bv.w};
      #pragma unroll
      for (int i = 0; i < 4; i++)
        #pragma unroll
        for (int j = 0; j < 4; j++)
          acc[i][j] += ar[i] * br[j];
    }
    __syncthreads();
  }
  float4 bi = *(const float4*)(bias + bn + tx*4);
  #pragma unroll
  for (int i = 0; i < 4; i++) {
    float4 o;
    o.x = acc[i][0] + bi.x; o.y = acc[i][1] + bi.y;
    o.z = acc[i][2] + bi.z; o.w = acc[i][3] + bi.w;
    *(float4*)(C + (size_t)(bm + ty*4 + i)*N + bn + tx*4) = o;
  }
}

// ---------------- logits GEMM: C = A @ Bt^T, with pad-mask ----------------
__global__ __launch_bounds__(256) void gemm_nt_logits(
    const float* __restrict__ A,   // P [2048, 512] (in d_ws — must NOT alias C)
    const float* __restrict__ Bt,  // emb [32000, 512]
    const int* __restrict__ ids,   // [2048]
    float* __restrict__ C) {       // [2048, 32000]
  const int K = EMBD, N = VOCAB;
  __shared__ float As[16][64];
  __shared__ float Bs[16][64];
  const int tid = threadIdx.x;
  const int bm = blockIdx.y * 64;
  const int bn = blockIdx.x * 64;
  const int tx = tid & 15, ty = tid >> 4;
  const int rA = tid >> 2, kq = (tid & 3) * 4;
  float acc[4][4] = {{0.f}};
  for (int k0 = 0; k0 < K; k0 += 16) {
    float4 a4 = *(const float4*)(A  + (size_t)(bm + rA)*K + k0 + kq);
    float4 b4 = *(const float4*)(Bt + (size_t)(bn + rA)*K + k0 + kq);
    As[kq+0][rA] = a4.x; As[kq+1][rA] = a4.y; As[kq+2][rA] = a4.z; As[kq+3][rA] = a4.w;
    Bs[kq+0][rA] = b4.x; Bs[kq+1][rA] = b4.y; Bs[kq+2][rA] = b4.z; Bs[kq+3][rA] = b4.w;
    __syncthreads();
    #pragma unroll
    for (int k = 0; k < 16; k++) {
      float4 av = *(float4*)&As[k][ty*4];
      float4 bv = *(float4*)&Bs[k][tx*4];
      float ar[4] = {av.x, av.y, av.z, av.w};
      float br[4] = {bv.x, bv.y, bv.z, bv.w};
      #pragma unroll
      for (int i = 0; i < 4; i++)
        #pragma unroll
        for (int j = 0; j < 4; j++)
          acc[i][j] += ar[i] * br[j];
    }
    __syncthreads();
  }
  #pragma unroll
  for (int i = 0; i < 4; i++) {
    const int row = bm + ty*4 + i;
    const bool mk = ids[row] != 0;
    float4 o;
    if (mk) { o.x = acc[i][0]; o.y = acc[i][1]; o.z = acc[i][2]; o.w = acc[i][3]; }
    else    { o.x = (bn + tx*4 == 0) ? 1.f : 0.f; o.y = 0.f; o.z = 0.f; o.w = 0.f; }
    *(float4*)(C + (size_t)row*N + bn + tx*4) = o;
  }
}

// ---------------- fused 2-layer pipelined LSTM recurrence -------------------
// Structure identical to round 11 (256 blocks x 256 thr, (256,1), A: Wr0 in
// regs; B: Wk1 in 128KB LDS + Wr1 in regs). ONE change: payload gathers
// (H0full rows, H1 rows) are PLAIN CACHED loads instead of device-scope
// atomics. These buffers are write-once per step (fresh addresses), so
// consumer L1/L2 can never hold stale copies; the first block per XCD pulls
// each line from MALL and the rest hit L2 -> MALL line-serves per step drop
// ~32x (was: every line served once per consumer block). Flags stay atomic
// (addresses reused). Producer publishes stay device-scope stores; vmcnt(0)
// before flag orders payload-before-flag at the coherence point.
__device__ __forceinline__ int rev5(int l) {
  return ((l & 1) << 4) | ((l & 2) << 2) | (l & 4) | ((l & 8) >> 2) | ((l & 16) >> 4);
}

#define HALVE(MASK, SH, HSZ)                          \
    { const int bit_ = (lane >> SH) & 1;              \
      _Pragma("unroll")                               \
      for (int j = 0; j < HSZ; j++) {                 \
        float snd = bit_ ? a[j] : a[j + HSZ];         \
        float kep = bit_ ? a[j + HSZ] : a[j];         \
        a[j] = kep + __shfl_xor(snd, MASK);           \
      } }

__global__ __launch_bounds__(256, 1) void lstm_fused(
    const float* __restrict__ Z0,     // [B*S, 4096] x@Wk0 + b0
    const float* __restrict__ Wr0T,   // [4096][1024]
    const float* __restrict__ Wk1T,   // [4096][1024]
    const float* __restrict__ Wr1T,   // [4096][1024]
    const float* __restrict__ bias1,  // [4096]
    const int* __restrict__ ids,      // [B*S]
    float* __restrict__ H1,           // [B*S, 1024] layer-1 h sequence
    float* __restrict__ H0full,       // [SLEN][4][1024] streamed h0
    unsigned* __restrict__ flgA,      // [128*16] (zeroed)
    unsigned* __restrict__ flgB) {    // [128*16] (zeroed)
  __shared__ float wk[32][1024];      // B only: Wk1 cols (128 KB)
  __shared__ float z_s[4][64];
  __shared__ float zc[128];
  const int tid  = threadIdx.x;
  const int lane = tid & 63;
  const int w    = tid >> 6;
  const int ccH  = tid >> 7;          // 0..1 (which 16 of the 32 gate cols)
  const int part = tid & 127;         // k-slice owner (8 k values per matrix)

  if (blockIdx.x < ABLK) {
    // ================= role A: layer-0, 8 units =================
    const int hbase = blockIdx.x * 8;
    float4 Wf[16], Wg[16];
    #pragma unroll
    for (int cl = 0; cl < 16; cl++) {
      const int cc = ccH * 16 + cl;
      const int g  = cc >> 3, d = cc & 7;
      const size_t col = (size_t)(g * HIDD + hbase + d);
      Wf[cl] = *(const float4*)(Wr0T + col * HIDD + 4 * part);
      Wg[cl] = *(const float4*)(Wr0T + col * HIDD + 512 + 4 * part);
    }
    float c_reg = 0.f, h_reg = 0.f;
    __syncthreads();

    for (int t = 0; t < SLEN; t++) {
      float pz0 = 0.f, pz1 = 0.f, pz2 = 0.f, pz3 = 0.f;
      int pmk = 0;
      if (tid < 32) {
        const int b = tid >> 3, d = tid & 7;
        const float* zrow = Z0 + (size_t)(b*SLEN + t) * GATE4 + hbase + d;
        pz0 = zrow[0];      pz1 = zrow[HIDD];
        pz2 = zrow[2*HIDD]; pz3 = zrow[3*HIDD];
        pmk = ids[b*SLEN + t];
      }
      float4 ha[NBAT], hb[NBAT];
      if (t > 0) {
        if (tid < ABLK) {
          while (AL(flgA + tid * 16) < (unsigned)t)
            __builtin_amdgcn_s_sleep(1);
        }
        __syncthreads();
        asm volatile("" ::: "memory");   // no load hoisting above the poll
        // plain cached gather of h0(t-1): write-once row -> no staleness;
        // XCD-mates share the L2 copy.
        const float* src = H0full + (size_t)(t - 1) * (NBAT*HIDD);
        #pragma unroll
        for (int b = 0; b < NBAT; b++) {
          ha[b] = *(const float4*)(src + b*HIDD + 4*part);
          hb[b] = *(const float4*)(src + b*HIDD + 512 + 4*part);
        }
      } else {
        #pragma unroll
        for (int b = 0; b < NBAT; b++) {
          ha[b] = make_float4(0.f, 0.f, 0.f, 0.f);
          hb[b] = make_float4(0.f, 0.f, 0.f, 0.f);
        }
      }
      float a[64];
      #pragma unroll
      for (int cl = 0; cl < 16; cl++)
        #pragma unroll
        for (int b = 0; b < NBAT; b++)
          a[cl*4 + b] = Wf[cl].x*ha[b].x + Wf[cl].y*ha[b].y
                      + Wf[cl].z*ha[b].z + Wf[cl].w*ha[b].w
                      + Wg[cl].x*hb[b].x + Wg[cl].y*hb[b].y
                      + Wg[cl].z*hb[b].z + Wg[cl].w*hb[b].w;
      #pragma unroll
      for (int i = 0; i < 64; i++) a[i] += __shfl_xor(a[i], 32);
      HALVE(1, 0, 32) HALVE(2, 1, 16) HALVE(4, 2, 8) HALVE(8, 3, 4) HALVE(16, 4, 2)
      if (lane < 32) {
        z_s[w][rev5(lane)*2 + 0] = a[0];
        z_s[w][rev5(lane)*2 + 1] = a[1];
      }
      __syncthreads();
      if (tid < 128) {
        const int cc = tid >> 2, b = tid & 3;
        const int cH = cc >> 4, i = ((cc & 15) << 2) | b;
        zc[tid] = z_s[2*cH][i] + z_s[2*cH + 1][i];
      }
      __syncthreads();
      if (tid < 32) {
        const int b = tid >> 3, d = tid & 7;
        const float zi = zc[((0*8 + d) << 2) + b] + pz0;
        const float zf = zc[((1*8 + d) << 2) + b] + pz1;
        const float zg = zc[((2*8 + d) << 2) + b] + pz2;
        const float zo = zc[((3*8 + d) << 2) + b] + pz3;
        const float ig = 1.f / (1.f + expf(-zi));
        const float fg = 1.f / (1.f + expf(-zf));
        const float gg = tanhf(zg);
        const float og = 1.f / (1.f + expf(-zo));
        const float cn = fg * c_reg + ig * gg;
        const float hn = og * tanhf(cn);
        const bool mk = pmk != 0;
        const float ho = mk ? hn : h_reg;
        c_reg = mk ? cn : c_reg;
        h_reg = ho;
        AS(H0full + (size_t)t * (NBAT*HIDD) + b*HIDD + hbase + d, ho);
      }
      if (w == 0) {
        asm volatile("s_waitcnt vmcnt(0)" ::: "memory");
        if (tid == 0)
          AS(flgA + blockIdx.x * 16, (unsigned)(t + 1));
      }
      __syncthreads();  // z_s/zc reuse safety
    }
  } else {
    // ================= role B: layer-1, 8 units =================
    const int bid = blockIdx.x - ABLK;   // 0..127
    const int ub  = bid * 8;
    // stage this block's 32 Wk1 columns into LDS (128 KB), coalesced
    for (int i = tid; i < 32 * 256; i += 256) {
      const int c2 = i >> 8, k4 = i & 255;
      const size_t col = (size_t)((c2 >> 3) * HIDD + ub + (c2 & 7));
      *(float4*)&wk[c2][k4 * 4] = *(const float4*)(Wk1T + col * HIDD + 4 * k4);
    }
    float4 Rf[16], Rg[16];
    #pragma unroll
    for (int cl = 0; cl < 16; cl++) {
      const int cc = ccH * 16 + cl;
      const int g  = cc >> 3, d = cc & 7;
      const size_t col = (size_t)(g * HIDD + ub + d);
      Rf[cl] = *(const float4*)(Wr1T + col * HIDD + 4 * part);
      Rg[cl] = *(const float4*)(Wr1T + col * HIDD + 512 + 4 * part);
    }
    float pbi = 0.f, pbf = 0.f, pbg = 0.f, pbo = 0.f;
    if (tid < 32) {
      const int d = tid & 7;
      pbi = bias1[0*HIDD + ub + d];
      pbf = bias1[1*HIDD + ub + d];
      pbg = bias1[2*HIDD + ub + d];
      pbo = bias1[3*HIDD + ub + d];
    }
    float c_reg = 0.f, h_reg = 0.f;
    __syncthreads();   // wk ready

    for (int t = 0; t < SLEN; t++) {
      int pmk = 0;
      if (tid < 32) pmk = ids[(tid >> 3) * SLEN + t];
      // parallel poll: lanes<128 watch flgA>=t+1; lanes 128..255 watch flgB>=t
      if (tid < 128) {
        while (AL(flgA + tid * 16) < (unsigned)(t + 1))
          __builtin_amdgcn_s_sleep(1);
      } else {
        while (AL(flgB + (tid - 128) * 16) < (unsigned)t)
          __builtin_amdgcn_s_sleep(1);
      }
      __syncthreads();
      asm volatile("" ::: "memory");   // no load hoisting above the poll
      // plain cached gathers (write-once rows): h0(t) and h1(t-1)
      float4 xa[NBAT], xb[NBAT], ya[NBAT], yb[NBAT];
      const float* h0p = H0full + (size_t)t * (NBAT*HIDD);
      #pragma unroll
      for (int b = 0; b < NBAT; b++) {
        xa[b] = *(const float4*)(h0p + b*HIDD + 4*part);
        xb[b] = *(const float4*)(h0p + b*HIDD + 512 + 4*part);
      }
      if (t > 0) {
        #pragma unroll
        for (int b = 0; b < NBAT; b++) {
          const float* h1r = H1 + (size_t)(b*SLEN + t - 1) * HIDD;
          ya[b] = *(const float4*)(h1r + 4*part);
          yb[b] = *(const float4*)(h1r + 512 + 4*part);
        }
      } else {
        #pragma unroll
        for (int b = 0; b < NBAT; b++) {
          ya[b] = make_float4(0.f, 0.f, 0.f, 0.f);
          yb[b] = make_float4(0.f, 0.f, 0.f, 0.f);
        }
      }
      // pass 1: z = Wk1(LDS) . h0(t)
      float a[64];
      #pragma unroll
      for (int cl = 0; cl < 16; cl++) {
        const int c2 = ccH * 16 + cl;
        const float4 kf = *(const float4*)&wk[c2][4 * part];
        const float4 kg = *(const float4*)&wk[c2][512 + 4 * part];
        #pragma unroll
        for (int b = 0; b < NBAT; b++) {
          a[cl*4 + b] = kf.x*xa[b].x + kf.y*xa[b].y + kf.z*xa[b].z + kf.w*xa[b].w
                      + kg.x*xb[b].x + kg.y*xb[b].y + kg.z*xb[b].z + kg.w*xb[b].w;
        }
      }
      // pass 2: z += Wr1(regs) . h1(t-1)
      #pragma unroll
      for (int cl = 0; cl < 16; cl++) {
        #pragma unroll
        for (int b = 0; b < NBAT; b++) {
          a[cl*4 + b] += Rf[cl].x*ya[b].x + Rf[cl].y*ya[b].y
                       + Rf[cl].z*ya[b].z + Rf[cl].w*ya[b].w
                       + Rg[cl].x*yb[b].x + Rg[cl].y*yb[b].y
                       + Rg[cl].z*yb[b].z + Rg[cl].w*yb[b].w;
        }
      }
      #pragma unroll
      for (int i = 0; i < 64; i++) a[i] += __shfl_xor(a[i], 32);
      HALVE(1, 0, 32) HALVE(2, 1, 16) HALVE(4, 2, 8) HALVE(8, 3, 4) HALVE(16, 4, 2)
      if (lane < 32) {
        z_s[w][rev5(lane)*2 + 0] = a[0];
        z_s[w][rev5(lane)*2 + 1] = a[1];
      }
      __syncthreads();
      if (tid < 128) {
        const int cc = tid >> 2, b = tid & 3;
        const int cH = cc >> 4, i = ((cc & 15) << 2) | b;
        zc[tid] = z_s[2*cH][i] + z_s[2*cH + 1][i];
      }
      __syncthreads();
      if (tid < 32) {
        const int b = tid >> 3, d = tid & 7;
        const float zi = zc[((0*8 + d) << 2) + b] + pbi;
        const float zf = zc[((1*8 + d) << 2) + b] + pbf;
        const float zg = zc[((2*8 + d) << 2) + b] + pbg;
        const float zo = zc[((3*8 + d) << 2) + b] + pbo;
        const float ig = 1.f / (1.f + expf(-zi));
        const float fg = 1.f / (1.f + expf(-zf));
        const float gg = tanhf(zg);
        const float og = 1.f / (1.f + expf(-zo));
        const float cn = fg * c_reg + ig * gg;
        const float hn = og * tanhf(cn);
        const bool mk = pmk != 0;
        const float ho = mk ? hn : h_reg;
        c_reg = mk ? cn : c_reg;
        h_reg = ho;
        AS(H1 + (size_t)(b*SLEN + t) * HIDD + ub + d, ho);
      }
      if (w == 0) {
        asm volatile("s_waitcnt vmcnt(0)" ::: "memory");
        if (tid == 0)
          AS(flgB + bid * 16, (unsigned)(t + 1));
      }
      __syncthreads();  // z_s/zc reuse safety
    }
  }
}
#undef HALVE

extern "C" void kernel_launch(void* const* d_in, const int* in_sizes, int n_in,
                              void* d_out, int out_size, void* d_ws, size_t ws_size,
                              hipStream_t stream) {
  const int*   ids = (const int*)  d_in[0];
  const float* emb = (const float*)d_in[1];
  const float* Wk0 = (const float*)d_in[2];
  const float* Wr0 = (const float*)d_in[3];
  const float* b0  = (const float*)d_in[4];
  const float* Wk1 = (const float*)d_in[5];
  const float* Wr1 = (const float*)d_in[6];
  const float* b1  = (const float*)d_in[7];
  const float* Wp  = (const float*)d_in[8];
  const float* bp  = (const float*)d_in[9];
  float* out = (float*)d_out;

  // DEAD-before-logits intermediates in the head of d_out; cross-kernel live
  // data (flags, P) in d_ws.
  float* X0     = out;                  // [2048,  512]  1,048,576 f
  float* Z      = out + 1048576;        // [2048, 4096]  8,388,608 f (L0)
  float* H1     = out + 9437184;        // [2048, 1024]  2,097,152 f
  float* Wr0T   = out + 11534336;       // [4096][1024]  4,194,304 f
  float* Wr1T   = out + 15728640;       // [4096][1024]  4,194,304 f
  float* Wk1T   = out + 19922944;       // [4096][1024]  4,194,304 f
  float* H0full = out + 24117248;       // [512][4096]   2,097,152 f
  unsigned* flgA = (unsigned*)d_ws;              // [128*16] u32 = 8 KB
  unsigned* flgB = (unsigned*)d_ws + 2048;       // [128*16] u32 = 8 KB
  float* P   = ((float*)d_ws) + 4096;   // [2048, 512] 1,048,576 f = 4 MB

  hipMemsetAsync(d_ws, 0, 16384, stream);  // zero both flag arrays
  embed_k<<<2048, 128, 0, stream>>>(ids, emb, X0);
  transpose_k<<<dim3(128, 32), 256, 0, stream>>>(Wr0, Wr0T);
  transpose_k<<<dim3(128, 32), 256, 0, stream>>>(Wr1, Wr1T);
  transpose_k<<<dim3(128, 32), 256, 0, stream>>>(Wk1, Wk1T);
  gemm_nn_bias<<<dim3(64, 32), 256, 0, stream>>>(X0, Wk0, b0, Z, 2048, 4096, 512);
  lstm_fused<<<ABLK + BBLK, 256, 0, stream>>>(Z, Wr0T, Wk1T, Wr1T, b1, ids,
                                              H1, H0full, flgA, flgB);
  gemm_nn_bias<<<dim3(8, 32), 256, 0, stream>>>(H1, Wp, bp, P, 2048, 512, 1024);
  gemm_nt_logits<<<dim3(500, 32), 256, 0, stream>>>(P, emb, ids, out);
}

// Round 13
// 4819.065 us; speedup vs baseline: 1.3063x; 1.3063x over previous
//
#include <hip/hip_runtime.h>

#define VOCAB 32000
#define EMBD  512
#define HIDD  1024
#define SLEN  512
#define NBAT  4
#define GATE4 4096   // 4*HIDD
#define ABLK  128    // layer-0 blocks, 8 units each
#define BBLK  128    // layer-1 blocks, 8 units each (Wk1 in LDS, Wr1 in regs)

typedef unsigned long long u64;

#define AL(p) __hip_atomic_load((p), __ATOMIC_RELAXED, __HIP_MEMORY_SCOPE_AGENT)
#define AS(p, v) __hip_atomic_store((p), (v), __ATOMIC_RELAXED, __HIP_MEMORY_SCOPE_AGENT)

__device__ __forceinline__ float2 u2f(u64 x) {
  return make_float2(__uint_as_float((unsigned)x),
                     __uint_as_float((unsigned)(x >> 32)));
}

// ---------------- 32x32 tiled transpose: [1024][4096] -> [4096][1024] -------
__global__ __launch_bounds__(256) void transpose_k(const float* __restrict__ src,
                                                   float* __restrict__ dst) {
  __shared__ float t[32][33];
  const int bx = blockIdx.x * 32;
  const int by = blockIdx.y * 32;
  const int r0 = threadIdx.x >> 5;
  const int c  = threadIdx.x & 31;
  #pragma unroll
  for (int i = 0; i < 4; i++) {
    const int r = r0 + i*8;
    t[r][c] = src[(size_t)(by + r)*GATE4 + bx + c];
  }
  __syncthreads();
  #pragma unroll
  for (int i = 0; i < 4; i++) {
    const int rw = r0 + i*8;
    dst[(size_t)(bx + rw)*HIDD + by + c] = t[c][rw];
  }
}

// -------- layer-0 input GEMM with fused embedding gather:
// Z[m][n] = sum_k emb[ids[m]][k] * Wk0[k][n] + b0[n]   (M=2048,N=4096,K=512)
__global__ __launch_bounds__(256) void gemm_nn_emb(
    const int* __restrict__ ids, const float* __restrict__ emb,
    const float* __restrict__ B, const float* __restrict__ bias,
    float* __restrict__ C, int N, int K) {
  __shared__ float As[16][64];
  __shared__ float Bs[16][64];
  const int tid = threadIdx.x;
  const int bm = blockIdx.y * 64;
  const int bn = blockIdx.x * 64;
  const int tx = tid & 15, ty = tid >> 4;
  const int mA = tid >> 2, kqA = (tid & 3) * 4;
  const int kB = tid >> 4, nB = (tid & 15) * 4;
  const int rid = ids[bm + mA];          // embedding row for this A row
  float acc[4][4] = {{0.f}};
  for (int k0 = 0; k0 < K; k0 += 16) {
    float4 a4 = *(const float4*)(emb + (size_t)rid*EMBD + k0 + kqA);
    As[kqA+0][mA] = a4.x; As[kqA+1][mA] = a4.y;
    As[kqA+2][mA] = a4.z; As[kqA+3][mA] = a4.w;
    *(float4*)&Bs[kB][nB] = *(const float4*)(B + (size_t)(k0 + kB)*N + bn + nB);
    __syncthreads();
    #pragma unroll
    for (int k = 0; k < 16; k++) {
      float4 av = *(float4*)&As[k][ty*4];
      float4 bv = *(float4*)&Bs[k][tx*4];
      float ar[4] = {av.x, av.y, av.z, av.w};
      float br[4] = {bv.x, bv.y, bv.z, bv.w};
      #pragma unroll
      for (int i = 0; i < 4; i++)
        #pragma unroll
        for (int j = 0; j < 4; j++)
          acc[i][j] += ar[i] * br[j];
    }
    __syncthreads();
  }
  float4 bi = *(const float4*)(bias + bn + tx*4);
  #pragma unroll
  for (int i = 0; i < 4; i++) {
    float4 o;
    o.x = acc[i][0] + bi.x; o.y = acc[i][1] + bi.y;
    o.z = acc[i][2] + bi.z; o.w = acc[i][3] + bi.w;
    *(float4*)(C + (size_t)(bm + ty*4 + i)*N + bn + tx*4) = o;
  }
}

// ---------------- f32 tiled GEMM: C = A@B + bias (64x64) ----------------
__global__ __launch_bounds__(256) void gemm_nn_bias(
    const float* __restrict__ A, const float* __restrict__ B,
    const float* __restrict__ bias, float* __restrict__ C,
    int M, int N, int K) {
  __shared__ float As[16][64];
  __shared__ float Bs[16][64];
  const int tid = threadIdx.x;
  const int bm = blockIdx.y * 64;
  const int bn = blockIdx.x * 64;
  const int tx = tid & 15, ty = tid >> 4;
  const int mA = tid >> 2, kqA = (tid & 3) * 4;
  const int kB = tid >> 4, nB = (tid & 15) * 4;
  float acc[4][4] = {{0.f}};
  for (int k0 = 0; k0 < K; k0 += 16) {
    float4 a4 = *(const float4*)(A + (size_t)(bm + mA)*K + k0 + kqA);
    As[kqA+0][mA] = a4.x; As[kqA+1][mA] = a4.y;
    As[kqA+2][mA] = a4.z; As[kqA+3][mA] = a4.w;
    *(float4*)&Bs[kB][nB] = *(const float4*)(B + (size_t)(k0 + kB)*N + bn + nB);
    __syncthreads();
    #pragma unroll
    for (int k = 0; k < 16; k++) {
      float4 av = *(float4*)&As[k][ty*4];
      float4 bv = *(float4*)&Bs[k][tx*4];
      float ar[4] = {av.x, av.y, av.z, av.w};
      float br[4] = {bv.x, bv.y, bv.z, bv.w};
      #pragma unroll
      for (int i = 0; i < 4; i++)
        #pragma unroll
        for (int j = 0; j < 4; j++)
          acc[i][j] += ar[i] * br[j];
    }
    __syncthreads();
  }
  float4 bi = *(const float4*)(bias + bn + tx*4);
  #pragma unroll
  for (int i = 0; i < 4; i++) {
    float4 o;
    o.x = acc[i][0] + bi.x; o.y = acc[i][1] + bi.y;
    o.z = acc[i][2] + bi.z; o.w = acc[i][3] + bi.w;
    *(float4*)(C + (size_t)(bm + ty*4 + i)*N + bn + tx*4) = o;
  }
}

// ------- logits GEMM, 128x128 tile, 8x8/thread: C = A @ Bt^T with pad-mask --
// Split 4+4 row/col groups keep LDS reads at <=2-way bank aliasing (free).
__global__ __launch_bounds__(256) void gemm_nt_logits128(
    const float* __restrict__ A,   // P [2048, 512] (in d_ws — not aliasing C)
    const float* __restrict__ Bt,  // emb [32000, 512]
    const int* __restrict__ ids,   // [2048]
    float* __restrict__ C) {       // [2048, 32000]
  const int K = EMBD, N = VOCAB;
  __shared__ float As[16][128];
  __shared__ float Bs[16][128];
  const int tid = threadIdx.x;
  const int bm = blockIdx.y * 128;
  const int bn = blockIdx.x * 128;
  const int tx = tid & 15, ty = tid >> 4;
  const int rL = tid >> 1, kL = (tid & 1) * 8;   // loader: row 0..127, k 0/8
  float acc[8][8] = {{0.f}};
  for (int k0 = 0; k0 < K; k0 += 16) {
    float4 a0 = *(const float4*)(A  + (size_t)(bm + rL)*K + k0 + kL);
    float4 a1 = *(const float4*)(A  + (size_t)(bm + rL)*K + k0 + kL + 4);
    float4 b0 = *(const float4*)(Bt + (size_t)(bn + rL)*K + k0 + kL);
    float4 b1 = *(const float4*)(Bt + (size_t)(bn + rL)*K + k0 + kL + 4);
    __syncthreads();   // previous iteration's LDS reads complete
    As[kL+0][rL] = a0.x; As[kL+1][rL] = a0.y; As[kL+2][rL] = a0.z; As[kL+3][rL] = a0.w;
    As[kL+4][rL] = a1.x; As[kL+5][rL] = a1.y; As[kL+6][rL] = a1.z; As[kL+7][rL] = a1.w;
    Bs[kL+0][rL] = b0.x; Bs[kL+1][rL] = b0.y; Bs[kL+2][rL] = b0.z; Bs[kL+3][rL] = b0.w;
    Bs[kL+4][rL] = b1.x; Bs[kL+5][rL] = b1.y; Bs[kL+6][rL] = b1.z; Bs[kL+7][rL] = b1.w;
    __syncthreads();
    #pragma unroll
    for (int k = 0; k < 16; k++) {
      float4 av0 = *(float4*)&As[k][ty*4];
      float4 av1 = *(float4*)&As[k][64 + ty*4];
      float4 bv0 = *(float4*)&Bs[k][tx*4];
      float4 bv1 = *(float4*)&Bs[k][64 + tx*4];
      float ar[8] = {av0.x, av0.y, av0.z, av0.w, av1.x, av1.y, av1.z, av1.w};
      float br[8] = {bv0.x, bv0.y, bv0.z, bv0.w, bv1.x, bv1.y, bv1.z, bv1.w};
      #pragma unroll
      for (int i = 0; i < 8; i++)
        #pragma unroll
        for (int j = 0; j < 8; j++)
          acc[i][j] += ar[i] * br[j];
    }
  }
  #pragma unroll
  for (int i = 0; i < 8; i++) {
    const int row = bm + ((i < 4) ? (ty*4 + i) : (64 + ty*4 + i - 4));
    const bool mk = ids[row] != 0;
    float4 o0, o1;
    if (mk) {
      o0 = make_float4(acc[i][0], acc[i][1], acc[i][2], acc[i][3]);
      o1 = make_float4(acc[i][4], acc[i][5], acc[i][6], acc[i][7]);
    } else {
      o0 = make_float4((bn + tx*4 == 0) ? 1.f : 0.f, 0.f, 0.f, 0.f);
      o1 = make_float4(0.f, 0.f, 0.f, 0.f);
    }
    *(float4*)(C + (size_t)row*N + bn + tx*4)      = o0;
    *(float4*)(C + (size_t)row*N + bn + 64 + tx*4) = o1;
  }
}

// ---------------- fused 2-layer pipelined LSTM recurrence -------------------
// EXACT round-11 structure (best measured: 3.93 ms, hop 7.7us, VGPR 216,
// zero spill). 256 blocks x 256 thr, (256,1). A: Wr0 in regs, streams h0(t)
// -> H0full (write-once; A waits only on flgA). B: Wk1 in 128KB LDS, Wr1 in
// regs; gathers h0(t)/h1(t-1) via relaxed device-scope u64 atomics (round-12
// showed plain cached loads miss MALL and go to HBM: slower).
__device__ __forceinline__ int rev5(int l) {
  return ((l & 1) << 4) | ((l & 2) << 2) | (l & 4) | ((l & 8) >> 2) | ((l & 16) >> 4);
}

#define HALVE(MASK, SH, HSZ)                          \
    { const int bit_ = (lane >> SH) & 1;              \
      _Pragma("unroll")                               \
      for (int j = 0; j < HSZ; j++) {                 \
        float snd = bit_ ? a[j] : a[j + HSZ];         \
        float kep = bit_ ? a[j + HSZ] : a[j];         \
        a[j] = kep + __shfl_xor(snd, MASK);           \
      } }

__global__ __launch_bounds__(256, 1) void lstm_fused(
    const float* __restrict__ Z0,     // [B*S, 4096] x@Wk0 + b0
    const float* __restrict__ Wr0T,   // [4096][1024]
    const float* __restrict__ Wk1T,   // [4096][1024]
    const float* __restrict__ Wr1T,   // [4096][1024]
    const float* __restrict__ bias1,  // [4096]
    const int* __restrict__ ids,      // [B*S]
    float* __restrict__ H1,           // [B*S, 1024] layer-1 h sequence
    float* __restrict__ H0full,       // [SLEN][4][1024] streamed h0
    unsigned* __restrict__ flgA,      // [128*16] (zeroed)
    unsigned* __restrict__ flgB) {    // [128*16] (zeroed)
  __shared__ float wk[32][1024];      // B only: Wk1 cols (128 KB)
  __shared__ float z_s[4][64];
  __shared__ float zc[128];
  const int tid  = threadIdx.x;
  const int lane = tid & 63;
  const int w    = tid >> 6;
  const int ccH  = tid >> 7;          // 0..1 (which 16 of the 32 gate cols)
  const int part = tid & 127;         // k-slice owner (8 k values per matrix)

  if (blockIdx.x < ABLK) {
    // ================= role A: layer-0, 8 units =================
    const int hbase = blockIdx.x * 8;
    float4 Wf[16], Wg[16];
    #pragma unroll
    for (int cl = 0; cl < 16; cl++) {
      const int cc = ccH * 16 + cl;
      const int g  = cc >> 3, d = cc & 7;
      const size_t col = (size_t)(g * HIDD + hbase + d);
      Wf[cl] = *(const float4*)(Wr0T + col * HIDD + 4 * part);
      Wg[cl] = *(const float4*)(Wr0T + col * HIDD + 512 + 4 * part);
    }
    float c_reg = 0.f, h_reg = 0.f;
    __syncthreads();

    for (int t = 0; t < SLEN; t++) {
      float pz0 = 0.f, pz1 = 0.f, pz2 = 0.f, pz3 = 0.f;
      int pmk = 0;
      if (tid < 32) {
        const int b = tid >> 3, d = tid & 7;
        const float* zrow = Z0 + (size_t)(b*SLEN + t) * GATE4 + hbase + d;
        pz0 = zrow[0];      pz1 = zrow[HIDD];
        pz2 = zrow[2*HIDD]; pz3 = zrow[3*HIDD];
        pmk = ids[b*SLEN + t];
      }
      float4 ha[NBAT], hb[NBAT];
      if (t > 0) {
        if (tid < ABLK) {
          while (AL(flgA + tid * 16) < (unsigned)t)
            __builtin_amdgcn_s_sleep(1);
        }
        __syncthreads();
        const u64* src = (const u64*)H0full + (size_t)(t - 1) * 2048;
        u64 v[16];
        #pragma unroll
        for (int b = 0; b < NBAT; b++) {
          v[b*4+0] = AL(src + b*512 + 2*part);
          v[b*4+1] = AL(src + b*512 + 2*part + 1);
          v[b*4+2] = AL(src + b*512 + 256 + 2*part);
          v[b*4+3] = AL(src + b*512 + 256 + 2*part + 1);
        }
        #pragma unroll
        for (int b = 0; b < NBAT; b++) {
          float2 p0 = u2f(v[b*4+0]), p1 = u2f(v[b*4+1]);
          float2 q0 = u2f(v[b*4+2]), q1 = u2f(v[b*4+3]);
          ha[b] = make_float4(p0.x, p0.y, p1.x, p1.y);
          hb[b] = make_float4(q0.x, q0.y, q1.x, q1.y);
        }
      } else {
        #pragma unroll
        for (int b = 0; b < NBAT; b++) {
          ha[b] = make_float4(0.f, 0.f, 0.f, 0.f);
          hb[b] = make_float4(0.f, 0.f, 0.f, 0.f);
        }
      }
      float a[64];
      #pragma unroll
      for (int cl = 0; cl < 16; cl++)
        #pragma unroll
        for (int b = 0; b < NBAT; b++)
          a[cl*4 + b] = Wf[cl].x*ha[b].x + Wf[cl].y*ha[b].y
                      + Wf[cl].z*ha[b].z + Wf[cl].w*ha[b].w
                      + Wg[cl].x*hb[b].x + Wg[cl].y*hb[b].y
                      + Wg[cl].z*hb[b].z + Wg[cl].w*hb[b].w;
      #pragma unroll
      for (int i = 0; i < 64; i++) a[i] += __shfl_xor(a[i], 32);
      HALVE(1, 0, 32) HALVE(2, 1, 16) HALVE(4, 2, 8) HALVE(8, 3, 4) HALVE(16, 4, 2)
      if (lane < 32) {
        z_s[w][rev5(lane)*2 + 0] = a[0];
        z_s[w][rev5(lane)*2 + 1] = a[1];
      }
      __syncthreads();
      if (tid < 128) {
        const int cc = tid >> 2, b = tid & 3;
        const int cH = cc >> 4, i = ((cc & 15) << 2) | b;
        zc[tid] = z_s[2*cH][i] + z_s[2*cH + 1][i];
      }
      __syncthreads();
      if (tid < 32) {
        const int b = tid >> 3, d = tid & 7;
        const float zi = zc[((0*8 + d) << 2) + b] + pz0;
        const float zf = zc[((1*8 + d) << 2) + b] + pz1;
        const float zg = zc[((2*8 + d) << 2) + b] + pz2;
        const float zo = zc[((3*8 + d) << 2) + b] + pz3;
        const float ig = 1.f / (1.f + expf(-zi));
        const float fg = 1.f / (1.f + expf(-zf));
        const float gg = tanhf(zg);
        const float og = 1.f / (1.f + expf(-zo));
        const float cn = fg * c_reg + ig * gg;
        const float hn = og * tanhf(cn);
        const bool mk = pmk != 0;
        const float ho = mk ? hn : h_reg;
        c_reg = mk ? cn : c_reg;
        h_reg = ho;
        AS(H0full + (size_t)t * (NBAT*HIDD) + b*HIDD + hbase + d, ho);
      }
      if (w == 0) {
        asm volatile("s_waitcnt vmcnt(0)" ::: "memory");
        if (tid == 0)
          AS(flgA + blockIdx.x * 16, (unsigned)(t + 1));
      }
      __syncthreads();  // z_s/zc reuse safety
    }
  } else {
    // ================= role B: layer-1, 8 units =================
    const int bid = blockIdx.x - ABLK;   // 0..127
    const int ub  = bid * 8;
    // stage this block's 32 Wk1 columns into LDS (128 KB), coalesced
    for (int i = tid; i < 32 * 256; i += 256) {
      const int c2 = i >> 8, k4 = i & 255;
      const size_t col = (size_t)((c2 >> 3) * HIDD + ub + (c2 & 7));
      *(float4*)&wk[c2][k4 * 4] = *(const float4*)(Wk1T + col * HIDD + 4 * k4);
    }
    float4 Rf[16], Rg[16];
    #pragma unroll
    for (int cl = 0; cl < 16; cl++) {
      const int cc = ccH * 16 + cl;
      const int g  = cc >> 3, d = cc & 7;
      const size_t col = (size_t)(g * HIDD + ub + d);
      Rf[cl] = *(const float4*)(Wr1T + col * HIDD + 4 * part);
      Rg[cl] = *(const float4*)(Wr1T + col * HIDD + 512 + 4 * part);
    }
    float pbi = 0.f, pbf = 0.f, pbg = 0.f, pbo = 0.f;
    if (tid < 32) {
      const int d = tid & 7;
      pbi = bias1[0*HIDD + ub + d];
      pbf = bias1[1*HIDD + ub + d];
      pbg = bias1[2*HIDD + ub + d];
      pbo = bias1[3*HIDD + ub + d];
    }
    float c_reg = 0.f, h_reg = 0.f;
    __syncthreads();   // wk ready

    for (int t = 0; t < SLEN; t++) {
      int pmk = 0;
      if (tid < 32) pmk = ids[(tid >> 3) * SLEN + t];
      // parallel poll: lanes<128 watch flgA>=t+1; lanes 128..255 watch flgB>=t
      if (tid < 128) {
        while (AL(flgA + tid * 16) < (unsigned)(t + 1))
          __builtin_amdgcn_s_sleep(1);
      } else {
        while (AL(flgB + (tid - 128) * 16) < (unsigned)t)
          __builtin_amdgcn_s_sleep(1);
      }
      __syncthreads();
      // gather h0(t) and h1(t-1) straight into registers (u64 = 2 floats)
      const u64* h0p = (const u64*)H0full + (size_t)t * 2048;
      u64 v0[16];
      #pragma unroll
      for (int b = 0; b < NBAT; b++) {
        v0[b*4+0] = AL(h0p + b*512 + 2*part);
        v0[b*4+1] = AL(h0p + b*512 + 2*part + 1);
        v0[b*4+2] = AL(h0p + b*512 + 256 + 2*part);
        v0[b*4+3] = AL(h0p + b*512 + 256 + 2*part + 1);
      }
      u64 v1[16];
      if (t > 0) {
        const u64* h1p = (const u64*)H1;
        #pragma unroll
        for (int b = 0; b < NBAT; b++) {
          const size_t row = (size_t)(b*SLEN + t - 1) * 512;
          v1[b*4+0] = AL(h1p + row + 2*part);
          v1[b*4+1] = AL(h1p + row + 2*part + 1);
          v1[b*4+2] = AL(h1p + row + 256 + 2*part);
          v1[b*4+3] = AL(h1p + row + 256 + 2*part + 1);
        }
      } else {
        #pragma unroll
        for (int r = 0; r < 16; r++) v1[r] = 0ull;
      }
      // pass 1: z = Wk1(LDS) . h0(t)
      float a[64];
      #pragma unroll
      for (int cl = 0; cl < 16; cl++) {
        const int c2 = ccH * 16 + cl;
        const float4 kf = *(const float4*)&wk[c2][4 * part];
        const float4 kg = *(const float4*)&wk[c2][512 + 4 * part];
        #pragma unroll
        for (int b = 0; b < NBAT; b++) {
          const float2 p0 = u2f(v0[b*4+0]), p1 = u2f(v0[b*4+1]);
          const float2 q0 = u2f(v0[b*4+2]), q1 = u2f(v0[b*4+3]);
          a[cl*4 + b] = kf.x*p0.x + kf.y*p0.y + kf.z*p1.x + kf.w*p1.y
                      + kg.x*q0.x + kg.y*q0.y + kg.z*q1.x + kg.w*q1.y;
        }
      }
      // pass 2: z += Wr1(regs) . h1(t-1)
      #pragma unroll
      for (int cl = 0; cl < 16; cl++) {
        #pragma unroll
        for (int b = 0; b < NBAT; b++) {
          const float2 p0 = u2f(v1[b*4+0]), p1 = u2f(v1[b*4+1]);
          const float2 q0 = u2f(v1[b*4+2]), q1 = u2f(v1[b*4+3]);
          a[cl*4 + b] += Rf[cl].x*p0.x + Rf[cl].y*p0.y + Rf[cl].z*p1.x + Rf[cl].w*p1.y
                       + Rg[cl].x*q0.x + Rg[cl].y*q0.y + Rg[cl].z*q1.x + Rg[cl].w*q1.y;
        }
      }
      #pragma unroll
      for (int i = 0; i < 64; i++) a[i] += __shfl_xor(a[i], 32);
      HALVE(1, 0, 32) HALVE(2, 1, 16) HALVE(4, 2, 8) HALVE(8, 3, 4) HALVE(16, 4, 2)
      if (lane < 32) {
        z_s[w][rev5(lane)*2 + 0] = a[0];
        z_s[w][rev5(lane)*2 + 1] = a[1];
      }
      __syncthreads();
      if (tid < 128) {
        const int cc = tid >> 2, b = tid & 3;
        const int cH = cc >> 4, i = ((cc & 15) << 2) | b;
        zc[tid] = z_s[2*cH][i] + z_s[2*cH + 1][i];
      }
      __syncthreads();
      if (tid < 32) {
        const int b = tid >> 3, d = tid & 7;
        const float zi = zc[((0*8 + d) << 2) + b] + pbi;
        const float zf = zc[((1*8 + d) << 2) + b] + pbf;
        const float zg = zc[((2*8 + d) << 2) + b] + pbg;
        const float zo = zc[((3*8 + d) << 2) + b] + pbo;
        const float ig = 1.f / (1.f + expf(-zi));
        const float fg = 1.f / (1.f + expf(-zf));
        const float gg = tanhf(zg);
        const float og = 1.f / (1.f + expf(-zo));
        const float cn = fg * c_reg + ig * gg;
        const float hn = og * tanhf(cn);
        const bool mk = pmk != 0;
        const float ho = mk ? hn : h_reg;
        c_reg = mk ? cn : c_reg;
        h_reg = ho;
        AS(H1 + (size_t)(b*SLEN + t) * HIDD + ub + d, ho);
      }
      if (w == 0) {
        asm volatile("s_waitcnt vmcnt(0)" ::: "memory");
        if (tid == 0)
          AS(flgB + bid * 16, (unsigned)(t + 1));
      }
      __syncthreads();  // z_s/zc reuse safety
    }
  }
}
#undef HALVE

extern "C" void kernel_launch(void* const* d_in, const int* in_sizes, int n_in,
                              void* d_out, int out_size, void* d_ws, size_t ws_size,
                              hipStream_t stream) {
  const int*   ids = (const int*)  d_in[0];
  const float* emb = (const float*)d_in[1];
  const float* Wk0 = (const float*)d_in[2];
  const float* Wr0 = (const float*)d_in[3];
  const float* b0  = (const float*)d_in[4];
  const float* Wk1 = (const float*)d_in[5];
  const float* Wr1 = (const float*)d_in[6];
  const float* b1  = (const float*)d_in[7];
  const float* Wp  = (const float*)d_in[8];
  const float* bp  = (const float*)d_in[9];
  float* out = (float*)d_out;

  // DEAD-before-logits intermediates in the head of d_out; cross-kernel live
  // data (flags, P) in d_ws.
  float* Z      = out;                  // [2048, 4096]  8,388,608 f (L0)
  float* H1     = out + 8388608;        // [2048, 1024]  2,097,152 f
  float* Wr0T   = out + 10485760;       // [4096][1024]  4,194,304 f
  float* Wr1T   = out + 14680064;       // [4096][1024]  4,194,304 f
  float* Wk1T   = out + 18874368;       // [4096][1024]  4,194,304 f
  float* H0full = out + 23068672;       // [512][4096]   2,097,152 f
  unsigned* flgA = (unsigned*)d_ws;              // [128*16] u32 = 8 KB
  unsigned* flgB = (unsigned*)d_ws + 2048;       // [128*16] u32 = 8 KB
  float* P   = ((float*)d_ws) + 4096;   // [2048, 512] 1,048,576 f = 4 MB

  hipMemsetAsync(d_ws, 0, 16384, stream);  // zero both flag arrays
  transpose_k<<<dim3(128, 32), 256, 0, stream>>>(Wr0, Wr0T);
  transpose_k<<<dim3(128, 32), 256, 0, stream>>>(Wr1, Wr1T);
  transpose_k<<<dim3(128, 32), 256, 0, stream>>>(Wk1, Wk1T);
  gemm_nn_emb<<<dim3(64, 32), 256, 0, stream>>>(ids, emb, Wk0, b0, Z, 4096, 512);
  lstm_fused<<<ABLK + BBLK, 256, 0, stream>>>(Z, Wr0T, Wk1T, Wr1T, b1, ids,
                                              H1, H0full, flgA, flgB);
  gemm_nn_bias<<<dim3(8, 32), 256, 0, stream>>>(H1, Wp, bp, P, 2048, 512, 1024);
  gemm_nt_logits128<<<dim3(250, 16), 256, 0, stream>>>(P, emb, ids, out);
}

// Round 14
// 4204.398 us; speedup vs baseline: 1.4973x; 1.1462x over previous
//
#include <hip/hip_runtime.h>

#define VOCAB 32000
#define EMBD  512
#define HIDD  1024
#define SLEN  512
#define NBAT  4
#define GATE4 4096   // 4*HIDD
#define ABLK  128    // layer-0 blocks, 8 units each
#define BBLK  128    // layer-1 blocks, 8 units each (Wk1 in LDS, Wr1 in regs)

typedef unsigned long long u64;

#define AL(p) __hip_atomic_load((p), __ATOMIC_RELAXED, __HIP_MEMORY_SCOPE_AGENT)
#define AS(p, v) __hip_atomic_store((p), (v), __ATOMIC_RELAXED, __HIP_MEMORY_SCOPE_AGENT)

// ---------------- 32x32 tiled transpose: [1024][4096] -> [4096][1024] -------
__global__ __launch_bounds__(256) void transpose_k(const float* __restrict__ src,
                                                   float* __restrict__ dst) {
  __shared__ float t[32][33];
  const int bx = blockIdx.x * 32;
  const int by = blockIdx.y * 32;
  const int r0 = threadIdx.x >> 5;
  const int c  = threadIdx.x & 31;
  #pragma unroll
  for (int i = 0; i < 4; i++) {
    const int r = r0 + i*8;
    t[r][c] = src[(size_t)(by + r)*GATE4 + bx + c];
  }
  __syncthreads();
  #pragma unroll
  for (int i = 0; i < 4; i++) {
    const int rw = r0 + i*8;
    dst[(size_t)(bx + rw)*HIDD + by + c] = t[c][rw];
  }
}

// -------- layer-0 input GEMM with fused embedding gather:
// Z[m][n] = sum_k emb[ids[m]][k] * Wk0[k][n] + b0[n]   (M=2048,N=4096,K=512)
__global__ __launch_bounds__(256) void gemm_nn_emb(
    const int* __restrict__ ids, const float* __restrict__ emb,
    const float* __restrict__ B, const float* __restrict__ bias,
    float* __restrict__ C, int N, int K) {
  __shared__ float As[16][64];
  __shared__ float Bs[16][64];
  const int tid = threadIdx.x;
  const int bm = blockIdx.y * 64;
  const int bn = blockIdx.x * 64;
  const int tx = tid & 15, ty = tid >> 4;
  const int mA = tid >> 2, kqA = (tid & 3) * 4;
  const int kB = tid >> 4, nB = (tid & 15) * 4;
  const int rid = ids[bm + mA];          // embedding row for this A row
  float acc[4][4] = {{0.f}};
  for (int k0 = 0; k0 < K; k0 += 16) {
    float4 a4 = *(const float4*)(emb + (size_t)rid*EMBD + k0 + kqA);
    As[kqA+0][mA] = a4.x; As[kqA+1][mA] = a4.y;
    As[kqA+2][mA] = a4.z; As[kqA+3][mA] = a4.w;
    *(float4*)&Bs[kB][nB] = *(const float4*)(B + (size_t)(k0 + kB)*N + bn + nB);
    __syncthreads();
    #pragma unroll
    for (int k = 0; k < 16; k++) {
      float4 av = *(float4*)&As[k][ty*4];
      float4 bv = *(float4*)&Bs[k][tx*4];
      float ar[4] = {av.x, av.y, av.z, av.w};
      float br[4] = {bv.x, bv.y, bv.z, bv.w};
      #pragma unroll
      for (int i = 0; i < 4; i++)
        #pragma unroll
        for (int j = 0; j < 4; j++)
          acc[i][j] += ar[i] * br[j];
    }
    __syncthreads();
  }
  float4 bi = *(const float4*)(bias + bn + tx*4);
  #pragma unroll
  for (int i = 0; i < 4; i++) {
    float4 o;
    o.x = acc[i][0] + bi.x; o.y = acc[i][1] + bi.y;
    o.z = acc[i][2] + bi.z; o.w = acc[i][3] + bi.w;
    *(float4*)(C + (size_t)(bm + ty*4 + i)*N + bn + tx*4) = o;
  }
}

// ---------------- f32 tiled GEMM: C = A@B + bias (64x64) ----------------
__global__ __launch_bounds__(256) void gemm_nn_bias(
    const float* __restrict__ A, const float* __restrict__ B,
    const float* __restrict__ bias, float* __restrict__ C,
    int M, int N, int K) {
  __shared__ float As[16][64];
  __shared__ float Bs[16][64];
  const int tid = threadIdx.x;
  const int bm = blockIdx.y * 64;
  const int bn = blockIdx.x * 64;
  const int tx = tid & 15, ty = tid >> 4;
  const int mA = tid >> 2, kqA = (tid & 3) * 4;
  const int kB = tid >> 4, nB = (tid & 15) * 4;
  float acc[4][4] = {{0.f}};
  for (int k0 = 0; k0 < K; k0 += 16) {
    float4 a4 = *(const float4*)(A + (size_t)(bm + mA)*K + k0 + kqA);
    As[kqA+0][mA] = a4.x; As[kqA+1][mA] = a4.y;
    As[kqA+2][mA] = a4.z; As[kqA+3][mA] = a4.w;
    *(float4*)&Bs[kB][nB] = *(const float4*)(B + (size_t)(k0 + kB)*N + bn + nB);
    __syncthreads();
    #pragma unroll
    for (int k = 0; k < 16; k++) {
      float4 av = *(float4*)&As[k][ty*4];
      float4 bv = *(float4*)&Bs[k][tx*4];
      float ar[4] = {av.x, av.y, av.z, av.w};
      float br[4] = {bv.x, bv.y, bv.z, bv.w};
      #pragma unroll
      for (int i = 0; i < 4; i++)
        #pragma unroll
        for (int j = 0; j < 4; j++)
          acc[i][j] += ar[i] * br[j];
    }
    __syncthreads();
  }
  float4 bi = *(const float4*)(bias + bn + tx*4);
  #pragma unroll
  for (int i = 0; i < 4; i++) {
    float4 o;
    o.x = acc[i][0] + bi.x; o.y = acc[i][1] + bi.y;
    o.z = acc[i][2] + bi.z; o.w = acc[i][3] + bi.w;
    *(float4*)(C + (size_t)(bm + ty*4 + i)*N + bn + tx*4) = o;
  }
}

// ------- logits GEMM, 128x128 tile, 8x8/thread: C = A @ Bt^T with pad-mask --
__global__ __launch_bounds__(256) void gemm_nt_logits128(
    const float* __restrict__ A,   // P [2048, 512] (in d_ws — not aliasing C)
    const float* __restrict__ Bt,  // emb [32000, 512]
    const int* __restrict__ ids,   // [2048]
    float* __restrict__ C) {       // [2048, 32000]
  const int K = EMBD, N = VOCAB;
  __shared__ float As[16][128];
  __shared__ float Bs[16][128];
  const int tid = threadIdx.x;
  const int bm = blockIdx.y * 128;
  const int bn = blockIdx.x * 128;
  const int tx = tid & 15, ty = tid >> 4;
  const int rL = tid >> 1, kL = (tid & 1) * 8;   // loader: row 0..127, k 0/8
  float acc[8][8] = {{0.f}};
  for (int k0 = 0; k0 < K; k0 += 16) {
    float4 a0 = *(const float4*)(A  + (size_t)(bm + rL)*K + k0 + kL);
    float4 a1 = *(const float4*)(A  + (size_t)(bm + rL)*K + k0 + kL + 4);
    float4 b0 = *(const float4*)(Bt + (size_t)(bn + rL)*K + k0 + kL);
    float4 b1 = *(const float4*)(Bt + (size_t)(bn + rL)*K + k0 + kL + 4);
    __syncthreads();   // previous iteration's LDS reads complete
    As[kL+0][rL] = a0.x; As[kL+1][rL] = a0.y; As[kL+2][rL] = a0.z; As[kL+3][rL] = a0.w;
    As[kL+4][rL] = a1.x; As[kL+5][rL] = a1.y; As[kL+6][rL] = a1.z; As[kL+7][rL] = a1.w;
    Bs[kL+0][rL] = b0.x; Bs[kL+1][rL] = b0.y; Bs[kL+2][rL] = b0.z; Bs[kL+3][rL] = b0.w;
    Bs[kL+4][rL] = b1.x; Bs[kL+5][rL] = b1.y; Bs[kL+6][rL] = b1.z; Bs[kL+7][rL] = b1.w;
    __syncthreads();
    #pragma unroll
    for (int k = 0; k < 16; k++) {
      float4 av0 = *(float4*)&As[k][ty*4];
      float4 av1 = *(float4*)&As[k][64 + ty*4];
      float4 bv0 = *(float4*)&Bs[k][tx*4];
      float4 bv1 = *(float4*)&Bs[k][64 + tx*4];
      float ar[8] = {av0.x, av0.y, av0.z, av0.w, av1.x, av1.y, av1.z, av1.w};
      float br[8] = {bv0.x, bv0.y, bv0.z, bv0.w, bv1.x, bv1.y, bv1.z, bv1.w};
      #pragma unroll
      for (int i = 0; i < 8; i++)
        #pragma unroll
        for (int j = 0; j < 8; j++)
          acc[i][j] += ar[i] * br[j];
    }
  }
  #pragma unroll
  for (int i = 0; i < 8; i++) {
    const int row = bm + ((i < 4) ? (ty*4 + i) : (64 + ty*4 + i - 4));
    const bool mk = ids[row] != 0;
    float4 o0, o1;
    if (mk) {
      o0 = make_float4(acc[i][0], acc[i][1], acc[i][2], acc[i][3]);
      o1 = make_float4(acc[i][4], acc[i][5], acc[i][6], acc[i][7]);
    } else {
      o0 = make_float4((bn + tx*4 == 0) ? 1.f : 0.f, 0.f, 0.f, 0.f);
      o1 = make_float4(0.f, 0.f, 0.f, 0.f);
    }
    *(float4*)(C + (size_t)row*N + bn + tx*4)      = o0;
    *(float4*)(C + (size_t)row*N + bn + 64 + tx*4) = o1;
  }
}

// ---------------- fused 2-layer pipelined LSTM recurrence -------------------
// Round-13 structure + two changes:
//  (1) DEDUPLICATED gathers: each block loads each h-u64 exactly ONCE
//      (8 u64/thread) into a 16KB LDS stage, then reads fragments via
//      conflict-free ds_read_b128. Halves MALL same-line request storm
//      (previously threads tid and tid+128 loaded identical addresses).
//  (2) B critical-path split: stage h0(t) + Wk1-pass BEFORE polling flgB
//      (A provably leads: lighter hop, never waits on B), so B's serial
//      chain is only {detect flgB -> stage h1 -> Wr1-pass -> reduce ->
//      gates -> publish}. h1 reuses the same LDS stage buffer.
// Deadlock-free in any schedule: A waits only on flgA; write-once buffers.
__device__ __forceinline__ int rev5(int l) {
  return ((l & 1) << 4) | ((l & 2) << 2) | (l & 4) | ((l & 8) >> 2) | ((l & 16) >> 4);
}

#define HALVE(MASK, SH, HSZ)                          \
    { const int bit_ = (lane >> SH) & 1;              \
      _Pragma("unroll")                               \
      for (int j = 0; j < HSZ; j++) {                 \
        float snd = bit_ ? a[j] : a[j + HSZ];         \
        float kep = bit_ ? a[j + HSZ] : a[j];         \
        a[j] = kep + __shfl_xor(snd, MASK);           \
      } }

__global__ __launch_bounds__(256, 1) void lstm_fused(
    const float* __restrict__ Z0,     // [B*S, 4096] x@Wk0 + b0
    const float* __restrict__ Wr0T,   // [4096][1024]
    const float* __restrict__ Wk1T,   // [4096][1024]
    const float* __restrict__ Wr1T,   // [4096][1024]
    const float* __restrict__ bias1,  // [4096]
    const int* __restrict__ ids,      // [B*S]
    float* __restrict__ H1,           // [B*S, 1024] layer-1 h sequence
    float* __restrict__ H0full,       // [SLEN][4][1024] streamed h0
    unsigned* __restrict__ flgA,      // [128*16] (zeroed)
    unsigned* __restrict__ flgB) {    // [128*16] (zeroed)
  __shared__ float wk[32][1024];      // B only: Wk1 cols (128 KB)
  __shared__ float hs[NBAT * HIDD];   // staged h vector (16 KB, reused)
  __shared__ float z_s[4][64];
  __shared__ float zc[128];
  const int tid  = threadIdx.x;
  const int lane = tid & 63;
  const int w    = tid >> 6;
  const int ccH  = tid >> 7;          // 0..1 (which 16 of the 32 gate cols)
  const int part = tid & 127;         // k-slice owner (8 k values per matrix)

  if (blockIdx.x < ABLK) {
    // ================= role A: layer-0, 8 units =================
    const int hbase = blockIdx.x * 8;
    float4 Wf[16], Wg[16];
    #pragma unroll
    for (int cl = 0; cl < 16; cl++) {
      const int cc = ccH * 16 + cl;
      const int g  = cc >> 3, d = cc & 7;
      const size_t col = (size_t)(g * HIDD + hbase + d);
      Wf[cl] = *(const float4*)(Wr0T + col * HIDD + 4 * part);
      Wg[cl] = *(const float4*)(Wr0T + col * HIDD + 512 + 4 * part);
    }
    float c_reg = 0.f, h_reg = 0.f;
    __syncthreads();

    for (int t = 0; t < SLEN; t++) {
      float pz0 = 0.f, pz1 = 0.f, pz2 = 0.f, pz3 = 0.f;
      int pmk = 0;
      if (tid < 32) {
        const int b = tid >> 3, d = tid & 7;
        const float* zrow = Z0 + (size_t)(b*SLEN + t) * GATE4 + hbase + d;
        pz0 = zrow[0];      pz1 = zrow[HIDD];
        pz2 = zrow[2*HIDD]; pz3 = zrow[3*HIDD];
        pmk = ids[b*SLEN + t];
      }
      float4 ha[NBAT], hb[NBAT];
      if (t > 0) {
        if (tid < ABLK) {
          while (AL(flgA + tid * 16) < (unsigned)t)
            __builtin_amdgcn_s_sleep(1);
        }
        __syncthreads();
        // dedup staged gather: 8 u64/thread, each address loaded once
        const u64* src = (const u64*)H0full + (size_t)(t - 1) * 2048;
        u64 v[8];
        #pragma unroll
        for (int r = 0; r < 8; r++)
          v[r] = AL(src + tid + (r << 8));
        #pragma unroll
        for (int r = 0; r < 8; r++)
          ((u64*)hs)[tid + (r << 8)] = v[r];
        __syncthreads();
        #pragma unroll
        for (int b = 0; b < NBAT; b++) {
          ha[b] = *(const float4*)(hs + b*HIDD + 4*part);
          hb[b] = *(const float4*)(hs + b*HIDD + 512 + 4*part);
        }
      } else {
        #pragma unroll
        for (int b = 0; b < NBAT; b++) {
          ha[b] = make_float4(0.f, 0.f, 0.f, 0.f);
          hb[b] = make_float4(0.f, 0.f, 0.f, 0.f);
        }
      }
      float a[64];
      #pragma unroll
      for (int cl = 0; cl < 16; cl++)
        #pragma unroll
        for (int b = 0; b < NBAT; b++)
          a[cl*4 + b] = Wf[cl].x*ha[b].x + Wf[cl].y*ha[b].y
                      + Wf[cl].z*ha[b].z + Wf[cl].w*ha[b].w
                      + Wg[cl].x*hb[b].x + Wg[cl].y*hb[b].y
                      + Wg[cl].z*hb[b].z + Wg[cl].w*hb[b].w;
      #pragma unroll
      for (int i = 0; i < 64; i++) a[i] += __shfl_xor(a[i], 32);
      HALVE(1, 0, 32) HALVE(2, 1, 16) HALVE(4, 2, 8) HALVE(8, 3, 4) HALVE(16, 4, 2)
      if (lane < 32) {
        z_s[w][rev5(lane)*2 + 0] = a[0];
        z_s[w][rev5(lane)*2 + 1] = a[1];
      }
      __syncthreads();
      if (tid < 128) {
        const int cc = tid >> 2, b = tid & 3;
        const int cH = cc >> 4, i = ((cc & 15) << 2) | b;
        zc[tid] = z_s[2*cH][i] + z_s[2*cH + 1][i];
      }
      __syncthreads();
      if (tid < 32) {
        const int b = tid >> 3, d = tid & 7;
        const float zi = zc[((0*8 + d) << 2) + b] + pz0;
        const float zf = zc[((1*8 + d) << 2) + b] + pz1;
        const float zg = zc[((2*8 + d) << 2) + b] + pz2;
        const float zo = zc[((3*8 + d) << 2) + b] + pz3;
        const float ig = 1.f / (1.f + expf(-zi));
        const float fg = 1.f / (1.f + expf(-zf));
        const float gg = tanhf(zg);
        const float og = 1.f / (1.f + expf(-zo));
        const float cn = fg * c_reg + ig * gg;
        const float hn = og * tanhf(cn);
        const bool mk = pmk != 0;
        const float ho = mk ? hn : h_reg;
        c_reg = mk ? cn : c_reg;
        h_reg = ho;
        AS(H0full + (size_t)t * (NBAT*HIDD) + b*HIDD + hbase + d, ho);
      }
      if (w == 0) {
        asm volatile("s_waitcnt vmcnt(0)" ::: "memory");
        if (tid == 0)
          AS(flgA + blockIdx.x * 16, (unsigned)(t + 1));
      }
      __syncthreads();  // hs/z_s/zc reuse safety
    }
  } else {
    // ================= role B: layer-1, 8 units =================
    const int bid = blockIdx.x - ABLK;   // 0..127
    const int ub  = bid * 8;
    // stage this block's 32 Wk1 columns into LDS (128 KB), coalesced
    for (int i = tid; i < 32 * 256; i += 256) {
      const int c2 = i >> 8, k4 = i & 255;
      const size_t col = (size_t)((c2 >> 3) * HIDD + ub + (c2 & 7));
      *(float4*)&wk[c2][k4 * 4] = *(const float4*)(Wk1T + col * HIDD + 4 * k4);
    }
    float4 Rf[16], Rg[16];
    #pragma unroll
    for (int cl = 0; cl < 16; cl++) {
      const int cc = ccH * 16 + cl;
      const int g  = cc >> 3, d = cc & 7;
      const size_t col = (size_t)(g * HIDD + ub + d);
      Rf[cl] = *(const float4*)(Wr1T + col * HIDD + 4 * part);
      Rg[cl] = *(const float4*)(Wr1T + col * HIDD + 512 + 4 * part);
    }
    float pbi = 0.f, pbf = 0.f, pbg = 0.f, pbo = 0.f;
    if (tid < 32) {
      const int d = tid & 7;
      pbi = bias1[0*HIDD + ub + d];
      pbf = bias1[1*HIDD + ub + d];
      pbg = bias1[2*HIDD + ub + d];
      pbo = bias1[3*HIDD + ub + d];
    }
    float c_reg = 0.f, h_reg = 0.f;
    __syncthreads();   // wk ready

    for (int t = 0; t < SLEN; t++) {
      int pmk = 0;
      if (tid < 32) pmk = ids[(tid >> 3) * SLEN + t];
      // ---- phase 1 (off the B-chain): h0(t) ready? A leads, so fast ----
      if (tid < 128) {
        while (AL(flgA + tid * 16) < (unsigned)(t + 1))
          __builtin_amdgcn_s_sleep(1);
      }
      __syncthreads();
      {  // dedup staged gather of h0(t)
        const u64* h0p = (const u64*)H0full + (size_t)t * 2048;
        u64 v[8];
        #pragma unroll
        for (int r = 0; r < 8; r++)
          v[r] = AL(h0p + tid + (r << 8));
        #pragma unroll
        for (int r = 0; r < 8; r++)
          ((u64*)hs)[tid + (r << 8)] = v[r];
      }
      __syncthreads();
      // pass 1: z = Wk1(LDS) . h0(t)  — before flgB poll
      float4 xa[NBAT], xb[NBAT];
      #pragma unroll
      for (int b = 0; b < NBAT; b++) {
        xa[b] = *(const float4*)(hs + b*HIDD + 4*part);
        xb[b] = *(const float4*)(hs + b*HIDD + 512 + 4*part);
      }
      float a[64];
      #pragma unroll
      for (int cl = 0; cl < 16; cl++) {
        const int c2 = ccH * 16 + cl;
        const float4 kf = *(const float4*)&wk[c2][4 * part];
        const float4 kg = *(const float4*)&wk[c2][512 + 4 * part];
        #pragma unroll
        for (int b = 0; b < NBAT; b++) {
          a[cl*4 + b] = kf.x*xa[b].x + kf.y*xa[b].y + kf.z*xa[b].z + kf.w*xa[b].w
                      + kg.x*xb[b].x + kg.y*xb[b].y + kg.z*xb[b].z + kg.w*xb[b].w;
        }
      }
      // ---- phase 2 (the B-chain): h1(t-1) ----
      if (t > 0) {
        if (tid < 128) {
          while (AL(flgB + tid * 16) < (unsigned)t)
            __builtin_amdgcn_s_sleep(1);
        }
        __syncthreads();   // also: all pass-1 hs reads complete
        {  // dedup staged gather of h1(t-1), reusing hs
          u64 v[8];
          #pragma unroll
          for (int r = 0; r < 8; r++) {
            const int idx = tid + (r << 8);
            const int b = idx >> 9, off = idx & 511;
            v[r] = AL((const u64*)H1 + (size_t)(b*SLEN + t - 1) * 512 + off);
          }
          #pragma unroll
          for (int r = 0; r < 8; r++)
            ((u64*)hs)[tid + (r << 8)] = v[r];
        }
        __syncthreads();
        float4 ya[NBAT], yb[NBAT];
        #pragma unroll
        for (int b = 0; b < NBAT; b++) {
          ya[b] = *(const float4*)(hs + b*HIDD + 4*part);
          yb[b] = *(const float4*)(hs + b*HIDD + 512 + 4*part);
        }
        // pass 2: z += Wr1(regs) . h1(t-1)
        #pragma unroll
        for (int cl = 0; cl < 16; cl++) {
          #pragma unroll
          for (int b = 0; b < NBAT; b++) {
            a[cl*4 + b] += Rf[cl].x*ya[b].x + Rf[cl].y*ya[b].y
                         + Rf[cl].z*ya[b].z + Rf[cl].w*ya[b].w
                         + Rg[cl].x*yb[b].x + Rg[cl].y*yb[b].y
                         + Rg[cl].z*yb[b].z + Rg[cl].w*yb[b].w;
          }
        }
      }
      #pragma unroll
      for (int i = 0; i < 64; i++) a[i] += __shfl_xor(a[i], 32);
      HALVE(1, 0, 32) HALVE(2, 1, 16) HALVE(4, 2, 8) HALVE(8, 3, 4) HALVE(16, 4, 2)
      if (lane < 32) {
        z_s[w][rev5(lane)*2 + 0] = a[0];
        z_s[w][rev5(lane)*2 + 1] = a[1];
      }
      __syncthreads();
      if (tid < 128) {
        const int cc = tid >> 2, b = tid & 3;
        const int cH = cc >> 4, i = ((cc & 15) << 2) | b;
        zc[tid] = z_s[2*cH][i] + z_s[2*cH + 1][i];
      }
      __syncthreads();
      if (tid < 32) {
        const int b = tid >> 3, d = tid & 7;
        const float zi = zc[((0*8 + d) << 2) + b] + pbi;
        const float zf = zc[((1*8 + d) << 2) + b] + pbf;
        const float zg = zc[((2*8 + d) << 2) + b] + pbg;
        const float zo = zc[((3*8 + d) << 2) + b] + pbo;
        const float ig = 1.f / (1.f + expf(-zi));
        const float fg = 1.f / (1.f + expf(-zf));
        const float gg = tanhf(zg);
        const float og = 1.f / (1.f + expf(-zo));
        const float cn = fg * c_reg + ig * gg;
        const float hn = og * tanhf(cn);
        const bool mk = pmk != 0;
        const float ho = mk ? hn : h_reg;
        c_reg = mk ? cn : c_reg;
        h_reg = ho;
        AS(H1 + (size_t)(b*SLEN + t) * HIDD + ub + d, ho);
      }
      if (w == 0) {
        asm volatile("s_waitcnt vmcnt(0)" ::: "memory");
        if (tid == 0)
          AS(flgB + bid * 16, (unsigned)(t + 1));
      }
      __syncthreads();  // hs/z_s/zc reuse safety
    }
  }
}
#undef HALVE

extern "C" void kernel_launch(void* const* d_in, const int* in_sizes, int n_in,
                              void* d_out, int out_size, void* d_ws, size_t ws_size,
                              hipStream_t stream) {
  const int*   ids = (const int*)  d_in[0];
  const float* emb = (const float*)d_in[1];
  const float* Wk0 = (const float*)d_in[2];
  const float* Wr0 = (const float*)d_in[3];
  const float* b0  = (const float*)d_in[4];
  const float* Wk1 = (const float*)d_in[5];
  const float* Wr1 = (const float*)d_in[6];
  const float* b1  = (const float*)d_in[7];
  const float* Wp  = (const float*)d_in[8];
  const float* bp  = (const float*)d_in[9];
  float* out = (float*)d_out;

  // DEAD-before-logits intermediates in the head of d_out; cross-kernel live
  // data (flags, P) in d_ws.
  float* Z      = out;                  // [2048, 4096]  8,388,608 f (L0)
  float* H1     = out + 8388608;        // [2048, 1024]  2,097,152 f
  float* Wr0T   = out + 10485760;       // [4096][1024]  4,194,304 f
  float* Wr1T   = out + 14680064;       // [4096][1024]  4,194,304 f
  float* Wk1T   = out + 18874368;       // [4096][1024]  4,194,304 f
  float* H0full = out + 23068672;       // [512][4096]   2,097,152 f
  unsigned* flgA = (unsigned*)d_ws;              // [128*16] u32 = 8 KB
  unsigned* flgB = (unsigned*)d_ws + 2048;       // [128*16] u32 = 8 KB
  float* P   = ((float*)d_ws) + 4096;   // [2048, 512] 1,048,576 f = 4 MB

  hipMemsetAsync(d_ws, 0, 16384, stream);  // zero both flag arrays
  transpose_k<<<dim3(128, 32), 256, 0, stream>>>(Wr0, Wr0T);
  transpose_k<<<dim3(128, 32), 256, 0, stream>>>(Wr1, Wr1T);
  transpose_k<<<dim3(128, 32), 256, 0, stream>>>(Wk1, Wk1T);
  gemm_nn_emb<<<dim3(64, 32), 256, 0, stream>>>(ids, emb, Wk0, b0, Z, 4096, 512);
  lstm_fused<<<ABLK + BBLK, 256, 0, stream>>>(Z, Wr0T, Wk1T, Wr1T, b1, ids,
                                              H1, H0full, flgA, flgB);
  gemm_nn_bias<<<dim3(8, 32), 256, 0, stream>>>(H1, Wp, bp, P, 2048, 512, 1024);
  gemm_nt_logits128<<<dim3(250, 16), 256, 0, stream>>>(P, emb, ids, out);
}